// Round 11
// baseline (106.508 us; speedup 1.0000x reference)
//
#include <hip/hip_runtime.h>
#include <hip/hip_bf16.h>

typedef __attribute__((ext_vector_type(8))) short bf16x8;   // MFMA A/B frag (4 VGPR)
typedef __attribute__((ext_vector_type(4))) float f32x4;    // MFMA C/D frag
typedef __attribute__((ext_vector_type(2))) float f32x2;

// may_alias everywhere for LDS + vector global loads (R1 lesson: TBAA DSE'd
// init stores -> stale-LDS divergence on graph replays).
typedef bf16x8 bf16x8_a __attribute__((may_alias));
typedef f32x4  f32x4_a  __attribute__((may_alias));
typedef f32x2  f32x2_a  __attribute__((may_alias));
typedef unsigned short u16a __attribute__((may_alias));
typedef unsigned int u32;

// Raw HW transcendentals (R4 win): v_exp_f32/v_rcp_f32, 1-ulp, tails saturate.
__device__ __forceinline__ float fexp2(float x) {
  float r; asm("v_exp_f32 %0, %1" : "=v"(r) : "v"(x)); return r;
}
__device__ __forceinline__ float frcp(float x) {
  float r; asm("v_rcp_f32 %0, %1" : "=v"(r) : "v"(x)); return r;
}
__device__ __forceinline__ float sigf(float x) {          // 1/(1+2^(-x*log2e))
  return frcp(1.f + fexp2(x * -1.44269504f));
}
__device__ __forceinline__ float tanhf_(float x) {        // 1 - 2/(1+2^(2x*log2e))
  return 1.f - 2.f * frcp(1.f + fexp2(x * 2.88539008f));
}
__device__ __forceinline__ u32 cvtpk(float lo, float hi) {
  u32 r; asm("v_cvt_pk_bf16_f32 %0, %1, %2" : "=v"(r) : "v"(lo), "v"(hi)); return r;
}

// LDS: WG = combined weights [192][64] bf16 (rows 0..127: W_s@w_out + W_hh for
// r,z; rows 128..191: W_s@w_out for i_n), swizzled 128-B rows.
// HB = double-buffered h state [2 buf][2 groups][16 rows][64] bf16, swizzled.
#define LDS_WG   0        // 24576
#define LDS_HB   24576    // + 8192
#define LDS_SIZE 32768

__device__ __forceinline__ void stbf(char* smem, int byteoff, float v) {
  union { __hip_bfloat16 b; unsigned short u; } cv;
  cv.b = __float2bfloat16(v);
  *(u16a*)(smem + byteoff) = cv.u;
}
__device__ __forceinline__ void st16(char* smem, int byteoff, unsigned short v) {
  *(u16a*)(smem + byteoff) = v;
}

__device__ __forceinline__ bf16x8 packf8(const float* v) {
  bf16x8 r;
  #pragma unroll
  for (int j = 0; j < 8; ++j) {
    union { __hip_bfloat16 b; short u; } cv;
    cv.b = __float2bfloat16(v[j]);
    r[j] = cv.u;
  }
  return r;
}

// Barrier, LDS-only drain (never vmcnt: out-stores stay in flight).
__device__ __forceinline__ void xbar() {
  asm volatile("s_waitcnt lgkmcnt(0)\n\ts_barrier" ::: "memory");
}

// R11: 128 blocks x 32 rows, 8 waves = TWO independent 16-row GRU groups per
// block (group p = w>>2, col-chunk wa = w&3). 2 waves/SIMD with FULL lanes and
// ONE barrier/step: each SIMD interleaves one wave of each group, so one
// group's MFMA/trans/ds latencies hide under the other's issue. (R5/R8 failed
// from lane-waste, R10 from barrier doubling; this cell has neither.)
// Also: all 10 MFMAs issue back-to-back before any sigmoid (no trans stall
// with empty MFMA pipe).
__global__ __launch_bounds__(512, 1)
void gru_fused(const float* __restrict__ s0, const float* __restrict__ a,
               const float* __restrict__ w_ih, const float* __restrict__ w_hh,
               const float* __restrict__ b_ih, const float* __restrict__ b_hh,
               const float* __restrict__ w_out, const float* __restrict__ b_out,
               float* __restrict__ out)
{
  __shared__ __align__(16) char smem[LDS_SIZE];
  const int tid = threadIdx.x;
  const int l = tid & 63;
  const int w = tid >> 6;          // wave id 0..7
  const int p = w >> 2;            // row-group 0,1 (rows 16p..16p+15)
  const int wa = w & 3;            // column-chunk id
  const int c = l & 15;
  const int g = l >> 4;
  const int b0 = blockIdx.x * 32;
  const int swzc = (c & 7) << 4;
  char* const hb_p = smem + LDS_HB + p * 2048;   // group's h rows; buf stride 4096

  // ---- stage s0 -> hbuf[0], 32 rows ----
  for (int idx = tid; idx < 32 * 64; idx += 512) {
    int r = idx >> 6, k = idx & 63;
    stbf(smem, LDS_HB + (r >> 4) * 2048 + (r & 15) * 128 + ((k * 2) ^ ((r & 7) << 4)),
         s0[(b0 + r) * 64 + k]);
  }

  // ---- prologue: WG = W_s @ w_out (+ W_hh for rows<128), f32-accum MFMA ----
  bf16x8 bwo[4][2];
  #pragma unroll
  for (int i = 0; i < 4; ++i) {
    #pragma unroll
    for (int ks = 0; ks < 2; ++ks) {
      float tv[8];
      #pragma unroll
      for (int j = 0; j < 8; ++j)
        tv[j] = w_out[(ks * 32 + g * 8 + j) * 64 + c + 16 * i];
      bwo[i][ks] = packf8(tv);
    }
  }
  #pragma unroll
  for (int rr = 0; rr < 2; ++rr) {
    int rt = w + 8 * rr;                       // row-tiles 0..15; guard < 12
    if (rt < 12) {
      bf16x8 wsa[2];
      #pragma unroll
      for (int ks = 0; ks < 2; ++ks) {
        float tv[8];
        #pragma unroll
        for (int u = 0; u < 4; ++u) {
          f32x2 t2 = *(const f32x2_a*)(w_ih + (16 * rt + c) * 66 + ks * 32 + g * 8 + 2 * u);
          tv[2 * u] = t2.x; tv[2 * u + 1] = t2.y;
        }
        wsa[ks] = packf8(tv);
      }
      f32x4 acc[4];
      #pragma unroll
      for (int i = 0; i < 4; ++i) {
        #pragma unroll
        for (int j = 0; j < 4; ++j) {
          int n = 16 * rt + 4 * g + j;
          acc[i][j] = (n < 128) ? w_hh[n * 64 + c + 16 * i] : 0.f;
        }
      }
      #pragma unroll
      for (int i = 0; i < 4; ++i)
        #pragma unroll
        for (int ks = 0; ks < 2; ++ks)
          acc[i] = __builtin_amdgcn_mfma_f32_16x16x32_bf16(wsa[ks], bwo[i][ks], acc[i], 0, 0, 0);
      #pragma unroll
      for (int i = 0; i < 4; ++i)
        #pragma unroll
        for (int j = 0; j < 4; ++j) {
          int n = 16 * rt + 4 * g + j;
          stbf(smem, LDS_WG + n * 128 + (((c + 16 * i) * 2) ^ ((n & 7) << 4)), acc[i][j]);
        }
    }
  }

  // ---- per-lane scalars ----
  const int nr = 16 * wa + c, nz = 64 + nr, ni = 128 + nr;
  float bs_r = 0.f, bs_z = 0.f, bs_i = 0.f;
  for (int d = 0; d < 64; ++d) {
    float bo = b_out[d];
    bs_r += w_ih[nr * 66 + d] * bo;
    bs_z += w_ih[nz * 66 + d] * bo;
    bs_i += w_ih[ni * 66 + d] * bo;
  }
  const float wa0_r = w_ih[nr * 66 + 64], wa1_r = w_ih[nr * 66 + 65];
  const float wa0_z = w_ih[nz * 66 + 64], wa1_z = w_ih[nz * 66 + 65];
  const float wa0_i = w_ih[ni * 66 + 64], wa1_i = w_ih[ni * 66 + 65];
  const float pb_r = b_ih[nr] + b_hh[nr];
  const float pb_z = b_ih[nz] + b_hh[nz];
  const float pb_i = b_ih[ni];
  const float bias_r = pb_r + bs_r;
  const float bias_z = pb_z + bs_z;
  const float bias_i = pb_i + bs_i;
  const float bias_hn = b_hh[ni];
  const float bias_o = b_out[nr];

  // ---- register B-frags straight from global ----
  bf16x8 whn[2], wo[2], wsr[2], wsz[2], wsi[2];
  #pragma unroll
  for (int ks = 0; ks < 2; ++ks) {
    float tv[8];
    f32x4 t4;
    t4 = *(const f32x4_a*)(w_hh + ni * 64 + ks * 32 + g * 8);
    tv[0] = t4.x; tv[1] = t4.y; tv[2] = t4.z; tv[3] = t4.w;
    t4 = *(const f32x4_a*)(w_hh + ni * 64 + ks * 32 + g * 8 + 4);
    tv[4] = t4.x; tv[5] = t4.y; tv[6] = t4.z; tv[7] = t4.w;
    whn[ks] = packf8(tv);
    t4 = *(const f32x4_a*)(w_out + nr * 64 + ks * 32 + g * 8);
    tv[0] = t4.x; tv[1] = t4.y; tv[2] = t4.z; tv[3] = t4.w;
    t4 = *(const f32x4_a*)(w_out + nr * 64 + ks * 32 + g * 8 + 4);
    tv[4] = t4.x; tv[5] = t4.y; tv[6] = t4.z; tv[7] = t4.w;
    wo[ks] = packf8(tv);
    #pragma unroll
    for (int u = 0; u < 4; ++u) {
      f32x2 t2 = *(const f32x2_a*)(w_ih + nr * 66 + ks * 32 + g * 8 + 2 * u);
      tv[2 * u] = t2.x; tv[2 * u + 1] = t2.y;
    }
    wsr[ks] = packf8(tv);
    #pragma unroll
    for (int u = 0; u < 4; ++u) {
      f32x2 t2 = *(const f32x2_a*)(w_ih + nz * 66 + ks * 32 + g * 8 + 2 * u);
      tv[2 * u] = t2.x; tv[2 * u + 1] = t2.y;
    }
    wsz[ks] = packf8(tv);
    #pragma unroll
    for (int u = 0; u < 4; ++u) {
      f32x2 t2 = *(const f32x2_a*)(w_ih + ni * 66 + ks * 32 + g * 8 + 2 * u);
      tv[2 * u] = t2.x; tv[2 * u + 1] = t2.y;
    }
    wsi[ks] = packf8(tv);
  }

  // ---- loop-invariant per-lane element offsets (group-local rows) ----
  int aoff[4], ooff[4];
  #pragma unroll
  for (int j = 0; j < 4; ++j) {
    int gr = b0 + 16 * p + 4 * g + j;
    aoff[j] = gr * 256;              // a row base (elements)
    ooff[j] = gr * 8192 + nr;        // out row base (elements), t-stride = 64
  }

  __syncthreads();   // staging + WG writes visible (full drain OK once)

  // WG B-frags from LDS (combined weights)
  bf16x8 wgr[2], wgz[2], wgi[2];
  #pragma unroll
  for (int ks = 0; ks < 2; ++ks) {
    wgr[ks] = *(const bf16x8_a*)(smem + LDS_WG + nr * 128 + ((ks * 64 + g * 16) ^ swzc));
    wgz[ks] = *(const bf16x8_a*)(smem + LDS_WG + nz * 128 + ((ks * 64 + g * 16) ^ swzc));
    wgi[ks] = *(const bf16x8_a*)(smem + LDS_WG + ni * 128 + ((ks * 64 + g * 16) ^ swzc));
  }

  // ---- peeled t=0: gates from explicit s0 (h0 = 0) ----
  bf16x8 sa[2];
  #pragma unroll
  for (int ks = 0; ks < 2; ++ks)
    sa[ks] = *(const bf16x8_a*)(hb_p + c * 128 + ((ks * 64 + g * 16) ^ swzc));
  f32x4 ar, az, ai;
  #pragma unroll
  for (int j = 0; j < 4; ++j) {
    f32x2 av = *(const f32x2_a*)(a + aoff[j]);          // a_0
    ar[j] = pb_r + av.x * wa0_r + av.y * wa1_r;
    az[j] = pb_z + av.x * wa0_z + av.y * wa1_z;
    ai[j] = pb_i + av.x * wa0_i + av.y * wa1_i;
  }
  #pragma unroll
  for (int ks = 0; ks < 2; ++ks) {
    ar = __builtin_amdgcn_mfma_f32_16x16x32_bf16(sa[ks], wsr[ks], ar, 0, 0, 0);
    az = __builtin_amdgcn_mfma_f32_16x16x32_bf16(sa[ks], wsz[ks], az, 0, 0, 0);
    ai = __builtin_amdgcn_mfma_f32_16x16x32_bf16(sa[ks], wsi[ks], ai, 0, 0, 0);
  }
  float hreg[4];
  #pragma unroll
  for (int j = 0; j < 4; ++j) {
    float r = sigf(ar[j]);
    float z = sigf(az[j]);
    float nn = tanhf_(ai[j] + r * bias_hn);
    hreg[j] = nn - z * nn;                        // h0 = 0
  }
  {
    u32 p01 = cvtpk(hreg[0], hreg[1]);
    u32 p23 = cvtpk(hreg[2], hreg[3]);
    int r0 = 4 * g;
    st16(hb_p, 4096 + (r0    ) * 128 + ((2 * nr) ^ (((r0    ) & 7) << 4)), (unsigned short)(p01));
    st16(hb_p, 4096 + (r0 + 1) * 128 + ((2 * nr) ^ (((r0 + 1) & 7) << 4)), (unsigned short)(p01 >> 16));
    st16(hb_p, 4096 + (r0 + 2) * 128 + ((2 * nr) ^ (((r0 + 2) & 7) << 4)), (unsigned short)(p23));
    st16(hb_p, 4096 + (r0 + 3) * 128 + ((2 * nr) ^ (((r0 + 3) & 7) << 4)), (unsigned short)(p23 >> 16));
  }
  // prefetch a_1 (avnA) / a_2 (avnB); each half-step reloads its set 2 ahead
  f32x2 avnA[4], avnB[4];
  #pragma unroll
  for (int j = 0; j < 4; ++j) {
    avnA[j] = *(const f32x2_a*)(a + 2 + aoff[j]);
    avnB[j] = *(const f32x2_a*)(a + 4 + aoff[j]);
  }
  xbar();

// One GRU half-step. RB/WB: compile-time buf byte offsets (0 / 4096).
// All 10 MFMAs issue back-to-back (arr,azz first -> their results ready when
// the first sigf issues; aii/ahh/ao latency hides under the sigmoid stall).
#define HALF_STEP(RB, WB, AV, APN, OB)                                         \
  {                                                                            \
    const char* hb = hb_p + (RB) + c * 128;                                    \
    bf16x8 ha0 = *(const bf16x8_a*)(hb + ((g * 16) ^ swzc));                   \
    bf16x8 ha1 = *(const bf16x8_a*)(hb + ((64 + g * 16) ^ swzc));              \
    f32x4 arr, azz, aii, ahh, ao;                                              \
    _Pragma("unroll")                                                          \
    for (int j = 0; j < 4; ++j) {                                              \
      arr[j] = bias_r + AV[j].x * wa0_r + AV[j].y * wa1_r;                     \
      azz[j] = bias_z + AV[j].x * wa0_z + AV[j].y * wa1_z;                     \
      aii[j] = bias_i + AV[j].x * wa0_i + AV[j].y * wa1_i;                     \
      ahh[j] = bias_hn;                                                        \
      ao[j]  = bias_o;                                                         \
    }                                                                          \
    _Pragma("unroll")                                                          \
    for (int j = 0; j < 4; ++j)                                                \
      AV[j] = *(const f32x2_a*)((APN) + aoff[j]);                              \
    arr = __builtin_amdgcn_mfma_f32_16x16x32_bf16(ha0, wgr[0], arr, 0, 0, 0);  \
    arr = __builtin_amdgcn_mfma_f32_16x16x32_bf16(ha1, wgr[1], arr, 0, 0, 0);  \
    azz = __builtin_amdgcn_mfma_f32_16x16x32_bf16(ha0, wgz[0], azz, 0, 0, 0);  \
    azz = __builtin_amdgcn_mfma_f32_16x16x32_bf16(ha1, wgz[1], azz, 0, 0, 0);  \
    aii = __builtin_amdgcn_mfma_f32_16x16x32_bf16(ha0, wgi[0], aii, 0, 0, 0);  \
    aii = __builtin_amdgcn_mfma_f32_16x16x32_bf16(ha1, wgi[1], aii, 0, 0, 0);  \
    ahh = __builtin_amdgcn_mfma_f32_16x16x32_bf16(ha0, whn[0], ahh, 0, 0, 0);  \
    ahh = __builtin_amdgcn_mfma_f32_16x16x32_bf16(ha1, whn[1], ahh, 0, 0, 0);  \
    ao  = __builtin_amdgcn_mfma_f32_16x16x32_bf16(ha0, wo[0],  ao,  0, 0, 0);  \
    ao  = __builtin_amdgcn_mfma_f32_16x16x32_bf16(ha1, wo[1],  ao,  0, 0, 0);  \
    float r_[4], z_[4];                                                        \
    _Pragma("unroll")                                                          \
    for (int j = 0; j < 4; ++j) { r_[j] = sigf(arr[j]); z_[j] = sigf(azz[j]); }\
    float hv[4];                                                               \
    _Pragma("unroll")                                                          \
    for (int j = 0; j < 4; ++j) {                                              \
      float nn = tanhf_(aii[j] + r_[j] * ahh[j]);                              \
      float h = nn + z_[j] * (hreg[j] - nn);                                   \
      hv[j] = h; hreg[j] = h;                                                  \
    }                                                                          \
    {                                                                          \
      u32 p01 = cvtpk(hv[0], hv[1]);                                           \
      u32 p23 = cvtpk(hv[2], hv[3]);                                           \
      int r0 = 4 * g;                                                          \
      char* hbn = hb_p + (WB);                                                 \
      st16(hbn, (r0    ) * 128 + ((2 * nr) ^ (((r0    ) & 7) << 4)), (unsigned short)(p01));       \
      st16(hbn, (r0 + 1) * 128 + ((2 * nr) ^ (((r0 + 1) & 7) << 4)), (unsigned short)(p01 >> 16)); \
      st16(hbn, (r0 + 2) * 128 + ((2 * nr) ^ (((r0 + 2) & 7) << 4)), (unsigned short)(p23));       \
      st16(hbn, (r0 + 3) * 128 + ((2 * nr) ^ (((r0 + 3) & 7) << 4)), (unsigned short)(p23 >> 16)); \
    }                                                                          \
    {                                                                          \
      float* ob = (OB);                                                        \
      _Pragma("unroll")                                                        \
      for (int j = 0; j < 4; ++j) ob[ooff[j]] = ao[j];                         \
    }                                                                          \
    xbar();                                                                    \
  }

  // ---- main loop: 63 pairs covering t = 1..126 ----
  #pragma unroll 1
  for (int tp = 0; tp < 63; ++tp) {
    const int t1 = 2 * tp + 1;                 // odd: reads buf1 (4096), writes buf0
    HALF_STEP(4096, 0, avnA, a + 2 * (t1 + 2), out + (size_t)(t1 - 1) * 64);
    const int t2n = (t1 + 3 <= 127) ? (t1 + 3) : 127;
    HALF_STEP(0, 4096, avnB, a + 2 * t2n, out + (size_t)t1 * 64);
  }

  // ---- t = 127 (odd: reads buf1, writes buf0); consumes avnA = a_127 ----
  HALF_STEP(4096, 0, avnA, a + 2 * 127, out + (size_t)126 * 64);

  // ---- epilogue: out[127] = h_128 @ w_out^T + b_out (h_128 in buf0) ----
  {
    const char* hb = hb_p + 0 + c * 128;
    bf16x8 ha0 = *(const bf16x8_a*)(hb + ((g * 16) ^ swzc));
    bf16x8 ha1 = *(const bf16x8_a*)(hb + ((64 + g * 16) ^ swzc));
    f32x4 ao = f32x4{bias_o, bias_o, bias_o, bias_o};
    ao = __builtin_amdgcn_mfma_f32_16x16x32_bf16(ha0, wo[0], ao, 0, 0, 0);
    ao = __builtin_amdgcn_mfma_f32_16x16x32_bf16(ha1, wo[1], ao, 0, 0, 0);
    float* ob = out + (size_t)127 * 64;
    #pragma unroll
    for (int j = 0; j < 4; ++j)
      ob[ooff[j]] = ao[j];
  }
#undef HALF_STEP
}

extern "C" void kernel_launch(void* const* d_in, const int* in_sizes, int n_in,
                              void* d_out, int out_size, void* d_ws, size_t ws_size,
                              hipStream_t stream) {
  const float* s0    = (const float*)d_in[0];
  const float* a     = (const float*)d_in[1];
  const float* w_ih  = (const float*)d_in[2];
  const float* w_hh  = (const float*)d_in[3];
  const float* b_ih  = (const float*)d_in[4];
  const float* b_hh  = (const float*)d_in[5];
  const float* w_out = (const float*)d_in[6];
  const float* b_out = (const float*)d_in[7];
  float* out = (float*)d_out;
  hipLaunchKernelGGL(gru_fused, dim3(4096 / 32), dim3(512), 0, stream,
                     s0, a, w_ih, w_hh, b_ih, b_hh, w_out, b_out, out);
}

// Round 12
// 73.909 us; speedup vs baseline: 1.4411x; 1.4411x over previous
//
#include <hip/hip_runtime.h>
#include <hip/hip_bf16.h>

typedef __attribute__((ext_vector_type(8))) short bf16x8;   // MFMA A/B frag (4 VGPR)
typedef __attribute__((ext_vector_type(4))) float f32x4;    // MFMA C/D frag
typedef __attribute__((ext_vector_type(2))) float f32x2;

// may_alias everywhere for LDS + vector global loads (R1 lesson: TBAA DSE'd
// init stores -> stale-LDS divergence on graph replays).
typedef bf16x8 bf16x8_a __attribute__((may_alias));
typedef f32x4  f32x4_a  __attribute__((may_alias));
typedef f32x2  f32x2_a  __attribute__((may_alias));
typedef unsigned short u16a __attribute__((may_alias));
typedef unsigned int u32;

// Raw HW transcendentals (R4 win): v_exp_f32/v_rcp_f32, 1-ulp, tails saturate.
__device__ __forceinline__ float fexp2(float x) {
  float r; asm("v_exp_f32 %0, %1" : "=v"(r) : "v"(x)); return r;
}
__device__ __forceinline__ float frcp(float x) {
  float r; asm("v_rcp_f32 %0, %1" : "=v"(r) : "v"(x)); return r;
}
__device__ __forceinline__ float sigf(float x) {          // 1/(1+2^(-x*log2e))
  return frcp(1.f + fexp2(x * -1.44269504f));
}
__device__ __forceinline__ float tanhf_(float x) {        // 1 - 2/(1+2^(2x*log2e))
  return 1.f - 2.f * frcp(1.f + fexp2(x * 2.88539008f));
}
__device__ __forceinline__ u32 cvtpk(float lo, float hi) {
  u32 r; asm("v_cvt_pk_bf16_f32 %0, %1, %2" : "=v"(r) : "v"(lo), "v"(hi)); return r;
}

// LDS: WG = combined weights [192][64] bf16 (rows 0..127: W_s@w_out + W_hh for
// r,z; rows 128..191: W_s@w_out for i_n), swizzled 128-B rows.
// HB = double-buffered h state [2][16 rows][64] bf16, swizzled.
#define LDS_WG   0        // 192 * 128 = 24576
#define LDS_HB   24576    // 2 * 16 * 128 = 4096
#define LDS_SIZE 28672

__device__ __forceinline__ void stbf(char* smem, int byteoff, float v) {
  union { __hip_bfloat16 b; unsigned short u; } cv;
  cv.b = __float2bfloat16(v);
  *(u16a*)(smem + byteoff) = cv.u;
}
__device__ __forceinline__ void st16(char* smem, int byteoff, unsigned short v) {
  *(u16a*)(smem + byteoff) = v;
}

__device__ __forceinline__ bf16x8 packf8(const float* v) {
  bf16x8 r;
  #pragma unroll
  for (int j = 0; j < 8; ++j) {
    union { __hip_bfloat16 b; short u; } cv;
    cv.b = __float2bfloat16(v[j]);
    r[j] = cv.u;
  }
  return r;
}

// Cross-wave barrier, LDS-only drain (never vmcnt: out-stores stay in flight).
__device__ __forceinline__ void xbar() {
  asm volatile("s_waitcnt lgkmcnt(0)\n\ts_barrier" ::: "memory");
}

// R12: R9 structure (proven best: 256 blocks x 16 rows x 4 waves, 1 barrier,
// full lanes; the ONLY config where B=4096=256CUx16 neither wastes lanes,
// doubles barriers, nor idles CUs — R5/R8/R10/R11 falsified the others).
// Change vs R9: ao-GEMM issued immediately after the gate MFMAs (independent,
// inputs ready) so the MFMA pipe executes it under the sigmoid/tanh trans
// stall instead of idling; stores stay late to fill the drain window.
__global__ __launch_bounds__(256, 1)
void gru_fused(const float* __restrict__ s0, const float* __restrict__ a,
               const float* __restrict__ w_ih, const float* __restrict__ w_hh,
               const float* __restrict__ b_ih, const float* __restrict__ b_hh,
               const float* __restrict__ w_out, const float* __restrict__ b_out,
               float* __restrict__ out)
{
  __shared__ __align__(16) char smem[LDS_SIZE];
  const int tid = threadIdx.x;
  const int l = tid & 63;
  const int w = tid >> 6;          // wave id 0..3
  const int c = l & 15;            // MFMA col/row lane
  const int g = l >> 4;            // k-group / row-group 0..3
  const int b0 = blockIdx.x * 16;
  const int swzc = (c & 7) << 4;

  // ---- stage s0 -> hbuf[0] ----
  for (int idx = tid; idx < 16 * 64; idx += 256) {
    int r = idx >> 6, k = idx & 63;
    stbf(smem, LDS_HB + r * 128 + ((k * 2) ^ ((r & 7) << 4)), s0[(b0 + r) * 64 + k]);
  }

  // ---- prologue: WG = W_s @ w_out (+ W_hh for rows<128), f32-accum MFMA ----
  bf16x8 bwo[4][2];
  #pragma unroll
  for (int i = 0; i < 4; ++i) {
    #pragma unroll
    for (int ks = 0; ks < 2; ++ks) {
      float tv[8];
      #pragma unroll
      for (int j = 0; j < 8; ++j)
        tv[j] = w_out[(ks * 32 + g * 8 + j) * 64 + c + 16 * i];
      bwo[i][ks] = packf8(tv);
    }
  }
  #pragma unroll
  for (int rr = 0; rr < 3; ++rr) {
    int rt = w + 4 * rr;                       // row-tiles 0..11 (n = 16rt..16rt+15)
    bf16x8 wsa[2];                             // A-frag: W_s row 16rt+c, k=dd
    #pragma unroll
    for (int ks = 0; ks < 2; ++ks) {
      float tv[8];
      #pragma unroll
      for (int u = 0; u < 4; ++u) {
        f32x2 t2 = *(const f32x2_a*)(w_ih + (16 * rt + c) * 66 + ks * 32 + g * 8 + 2 * u);
        tv[2 * u] = t2.x; tv[2 * u + 1] = t2.y;
      }
      wsa[ks] = packf8(tv);
    }
    f32x4 acc[4];
    #pragma unroll
    for (int i = 0; i < 4; ++i) {
      #pragma unroll
      for (int j = 0; j < 4; ++j) {
        int n = 16 * rt + 4 * g + j;
        acc[i][j] = (n < 128) ? w_hh[n * 64 + c + 16 * i] : 0.f;
      }
    }
    #pragma unroll
    for (int i = 0; i < 4; ++i)
      #pragma unroll
      for (int ks = 0; ks < 2; ++ks)
        acc[i] = __builtin_amdgcn_mfma_f32_16x16x32_bf16(wsa[ks], bwo[i][ks], acc[i], 0, 0, 0);
    #pragma unroll
    for (int i = 0; i < 4; ++i)
      #pragma unroll
      for (int j = 0; j < 4; ++j) {
        int n = 16 * rt + 4 * g + j;
        stbf(smem, LDS_WG + n * 128 + (((c + 16 * i) * 2) ^ ((n & 7) << 4)), acc[i][j]);
      }
  }

  // ---- per-lane scalars ----
  const int nr = 16 * w + c, nz = 64 + nr, ni = 128 + nr;
  float bs_r = 0.f, bs_z = 0.f, bs_i = 0.f;
  for (int d = 0; d < 64; ++d) {
    float bo = b_out[d];
    bs_r += w_ih[nr * 66 + d] * bo;
    bs_z += w_ih[nz * 66 + d] * bo;
    bs_i += w_ih[ni * 66 + d] * bo;
  }
  const float wa0_r = w_ih[nr * 66 + 64], wa1_r = w_ih[nr * 66 + 65];
  const float wa0_z = w_ih[nz * 66 + 64], wa1_z = w_ih[nz * 66 + 65];
  const float wa0_i = w_ih[ni * 66 + 64], wa1_i = w_ih[ni * 66 + 65];
  const float pb_r = b_ih[nr] + b_hh[nr];
  const float pb_z = b_ih[nz] + b_hh[nz];
  const float pb_i = b_ih[ni];
  const float bias_r = pb_r + bs_r;
  const float bias_z = pb_z + bs_z;
  const float bias_i = pb_i + bs_i;
  const float bias_hn = b_hh[ni];
  const float bias_o = b_out[nr];

  // ---- register B-frags straight from global ----
  bf16x8 whn[2], wo[2], wsr[2], wsz[2], wsi[2];
  #pragma unroll
  for (int ks = 0; ks < 2; ++ks) {
    float tv[8];
    f32x4 t4;
    t4 = *(const f32x4_a*)(w_hh + ni * 64 + ks * 32 + g * 8);
    tv[0] = t4.x; tv[1] = t4.y; tv[2] = t4.z; tv[3] = t4.w;
    t4 = *(const f32x4_a*)(w_hh + ni * 64 + ks * 32 + g * 8 + 4);
    tv[4] = t4.x; tv[5] = t4.y; tv[6] = t4.z; tv[7] = t4.w;
    whn[ks] = packf8(tv);
    t4 = *(const f32x4_a*)(w_out + nr * 64 + ks * 32 + g * 8);
    tv[0] = t4.x; tv[1] = t4.y; tv[2] = t4.z; tv[3] = t4.w;
    t4 = *(const f32x4_a*)(w_out + nr * 64 + ks * 32 + g * 8 + 4);
    tv[4] = t4.x; tv[5] = t4.y; tv[6] = t4.z; tv[7] = t4.w;
    wo[ks] = packf8(tv);
    #pragma unroll
    for (int u = 0; u < 4; ++u) {
      f32x2 t2 = *(const f32x2_a*)(w_ih + nr * 66 + ks * 32 + g * 8 + 2 * u);
      tv[2 * u] = t2.x; tv[2 * u + 1] = t2.y;
    }
    wsr[ks] = packf8(tv);
    #pragma unroll
    for (int u = 0; u < 4; ++u) {
      f32x2 t2 = *(const f32x2_a*)(w_ih + nz * 66 + ks * 32 + g * 8 + 2 * u);
      tv[2 * u] = t2.x; tv[2 * u + 1] = t2.y;
    }
    wsz[ks] = packf8(tv);
    #pragma unroll
    for (int u = 0; u < 4; ++u) {
      f32x2 t2 = *(const f32x2_a*)(w_ih + ni * 66 + ks * 32 + g * 8 + 2 * u);
      tv[2 * u] = t2.x; tv[2 * u + 1] = t2.y;
    }
    wsi[ks] = packf8(tv);
  }

  // ---- loop-invariant per-lane element offsets (saddr-form addressing) ----
  int aoff[4], ooff[4];
  #pragma unroll
  for (int j = 0; j < 4; ++j) {
    int gr = b0 + 4 * g + j;
    aoff[j] = gr * 256;              // a row base (elements)
    ooff[j] = gr * 8192 + nr;        // out row base (elements), t-stride = 64
  }

  __syncthreads();   // staging + WG writes visible (full drain OK once)

  // WG B-frags from LDS (combined weights)
  bf16x8 wgr[2], wgz[2], wgi[2];
  #pragma unroll
  for (int ks = 0; ks < 2; ++ks) {
    wgr[ks] = *(const bf16x8_a*)(smem + LDS_WG + nr * 128 + ((ks * 64 + g * 16) ^ swzc));
    wgz[ks] = *(const bf16x8_a*)(smem + LDS_WG + nz * 128 + ((ks * 64 + g * 16) ^ swzc));
    wgi[ks] = *(const bf16x8_a*)(smem + LDS_WG + ni * 128 + ((ks * 64 + g * 16) ^ swzc));
  }

  // ---- peeled t=0: gates from explicit s0 (h0 = 0) ----
  bf16x8 sa[2];
  #pragma unroll
  for (int ks = 0; ks < 2; ++ks)
    sa[ks] = *(const bf16x8_a*)(smem + LDS_HB + c * 128 + ((ks * 64 + g * 16) ^ swzc));
  f32x4 ar, az, ai;
  #pragma unroll
  for (int j = 0; j < 4; ++j) {
    f32x2 av = *(const f32x2_a*)(a + aoff[j]);          // a_0
    ar[j] = pb_r + av.x * wa0_r + av.y * wa1_r;
    az[j] = pb_z + av.x * wa0_z + av.y * wa1_z;
    ai[j] = pb_i + av.x * wa0_i + av.y * wa1_i;
  }
  #pragma unroll
  for (int ks = 0; ks < 2; ++ks) {
    ar = __builtin_amdgcn_mfma_f32_16x16x32_bf16(sa[ks], wsr[ks], ar, 0, 0, 0);
    az = __builtin_amdgcn_mfma_f32_16x16x32_bf16(sa[ks], wsz[ks], az, 0, 0, 0);
    ai = __builtin_amdgcn_mfma_f32_16x16x32_bf16(sa[ks], wsi[ks], ai, 0, 0, 0);
  }
  float hreg[4];
  #pragma unroll
  for (int j = 0; j < 4; ++j) {
    float r = sigf(ar[j]);
    float z = sigf(az[j]);
    float nn = tanhf_(ai[j] + r * bias_hn);
    hreg[j] = nn - z * nn;                        // h0 = 0
  }
  {
    u32 p01 = cvtpk(hreg[0], hreg[1]);
    u32 p23 = cvtpk(hreg[2], hreg[3]);
    int r0 = 4 * g;
    st16(smem, LDS_HB + 2048 + (r0    ) * 128 + ((2 * nr) ^ (((r0    ) & 7) << 4)), (unsigned short)(p01));
    st16(smem, LDS_HB + 2048 + (r0 + 1) * 128 + ((2 * nr) ^ (((r0 + 1) & 7) << 4)), (unsigned short)(p01 >> 16));
    st16(smem, LDS_HB + 2048 + (r0 + 2) * 128 + ((2 * nr) ^ (((r0 + 2) & 7) << 4)), (unsigned short)(p23));
    st16(smem, LDS_HB + 2048 + (r0 + 3) * 128 + ((2 * nr) ^ (((r0 + 3) & 7) << 4)), (unsigned short)(p23 >> 16));
  }
  // prefetch a_1 (avnA) and a_2 (avnB): each half-step reloads its own set
  // 2 steps ahead -> ~1500 cyc slack, no register copies.
  f32x2 avnA[4], avnB[4];
  #pragma unroll
  for (int j = 0; j < 4; ++j) {
    avnA[j] = *(const f32x2_a*)(a + 2 + aoff[j]);
    avnB[j] = *(const f32x2_a*)(a + 4 + aoff[j]);
  }
  xbar();

// One GRU half-step. RB/WB: compile-time LDS h-buffer byte offsets.
// AV: the a_t register set consumed AND reloaded (for t+2, base APN).
// Ordering: gate MFMAs -> ao MFMAs (independent; MFMA pipe runs them under
// the trans stall) -> r,z sigmoids -> tanh/blend -> h-write -> stores -> bar.
#define HALF_STEP(RB, WB, AV, APN, OB)                                         \
  {                                                                            \
    const char* hb = smem + LDS_HB + (RB) + c * 128;                           \
    bf16x8 ha0 = *(const bf16x8_a*)(hb + ((g * 16) ^ swzc));                   \
    bf16x8 ha1 = *(const bf16x8_a*)(hb + ((64 + g * 16) ^ swzc));              \
    f32x4 arr, azz, aii, ahh, ao;                                              \
    _Pragma("unroll")                                                          \
    for (int j = 0; j < 4; ++j) {                                              \
      arr[j] = bias_r + AV[j].x * wa0_r + AV[j].y * wa1_r;                     \
      azz[j] = bias_z + AV[j].x * wa0_z + AV[j].y * wa1_z;                     \
      aii[j] = bias_i + AV[j].x * wa0_i + AV[j].y * wa1_i;                     \
      ahh[j] = bias_hn;                                                        \
      ao[j]  = bias_o;                                                         \
    }                                                                          \
    _Pragma("unroll")                                                          \
    for (int j = 0; j < 4; ++j)                                                \
      AV[j] = *(const f32x2_a*)((APN) + aoff[j]);                              \
    arr = __builtin_amdgcn_mfma_f32_16x16x32_bf16(ha0, wgr[0], arr, 0, 0, 0);  \
    arr = __builtin_amdgcn_mfma_f32_16x16x32_bf16(ha1, wgr[1], arr, 0, 0, 0);  \
    azz = __builtin_amdgcn_mfma_f32_16x16x32_bf16(ha0, wgz[0], azz, 0, 0, 0);  \
    azz = __builtin_amdgcn_mfma_f32_16x16x32_bf16(ha1, wgz[1], azz, 0, 0, 0);  \
    aii = __builtin_amdgcn_mfma_f32_16x16x32_bf16(ha0, wgi[0], aii, 0, 0, 0);  \
    aii = __builtin_amdgcn_mfma_f32_16x16x32_bf16(ha1, wgi[1], aii, 0, 0, 0);  \
    ahh = __builtin_amdgcn_mfma_f32_16x16x32_bf16(ha0, whn[0], ahh, 0, 0, 0);  \
    ahh = __builtin_amdgcn_mfma_f32_16x16x32_bf16(ha1, whn[1], ahh, 0, 0, 0);  \
    ao  = __builtin_amdgcn_mfma_f32_16x16x32_bf16(ha0, wo[0],  ao,  0, 0, 0);  \
    ao  = __builtin_amdgcn_mfma_f32_16x16x32_bf16(ha1, wo[1],  ao,  0, 0, 0);  \
    float r_[4], z_[4];                                                        \
    _Pragma("unroll")                                                          \
    for (int j = 0; j < 4; ++j) { r_[j] = sigf(arr[j]); z_[j] = sigf(azz[j]); }\
    float hv[4];                                                               \
    _Pragma("unroll")                                                          \
    for (int j = 0; j < 4; ++j) {                                              \
      float nn = tanhf_(aii[j] + r_[j] * ahh[j]);                              \
      float h = nn + z_[j] * (hreg[j] - nn);                                   \
      hv[j] = h; hreg[j] = h;                                                  \
    }                                                                          \
    {                                                                          \
      u32 p01 = cvtpk(hv[0], hv[1]);                                           \
      u32 p23 = cvtpk(hv[2], hv[3]);                                           \
      int r0 = 4 * g;                                                          \
      char* hbn = smem + LDS_HB + (WB);                                        \
      st16(hbn, (r0    ) * 128 + ((2 * nr) ^ (((r0    ) & 7) << 4)), (unsigned short)(p01));       \
      st16(hbn, (r0 + 1) * 128 + ((2 * nr) ^ (((r0 + 1) & 7) << 4)), (unsigned short)(p01 >> 16)); \
      st16(hbn, (r0 + 2) * 128 + ((2 * nr) ^ (((r0 + 2) & 7) << 4)), (unsigned short)(p23));       \
      st16(hbn, (r0 + 3) * 128 + ((2 * nr) ^ (((r0 + 3) & 7) << 4)), (unsigned short)(p23 >> 16)); \
    }                                                                          \
    {                                                                          \
      float* ob = (OB);                                                        \
      _Pragma("unroll")                                                        \
      for (int j = 0; j < 4; ++j) ob[ooff[j]] = ao[j];                         \
    }                                                                          \
    xbar();                                                                    \
  }

  // ---- main loop: 63 pairs covering t = 1..126 ----
  #pragma unroll 1
  for (int tp = 0; tp < 63; ++tp) {
    const int t1 = 2 * tp + 1;                 // odd: reads HB1, writes HB0
    HALF_STEP(2048, 0, avnA, a + 2 * (t1 + 2), out + (size_t)(t1 - 1) * 64);
    const int t2n = (t1 + 3 <= 127) ? (t1 + 3) : 127;
    HALF_STEP(0, 2048, avnB, a + 2 * t2n, out + (size_t)t1 * 64);
  }

  // ---- t = 127 (odd: reads HB1, writes HB0); consumes avnA = a_127 ----
  HALF_STEP(2048, 0, avnA, a + 2 * 127, out + (size_t)126 * 64);

  // ---- epilogue: out[127] = h_128 @ w_out^T + b_out (h_128 in HB0) ----
  {
    const char* hb = smem + LDS_HB + 0 + c * 128;
    bf16x8 ha0 = *(const bf16x8_a*)(hb + ((g * 16) ^ swzc));
    bf16x8 ha1 = *(const bf16x8_a*)(hb + ((64 + g * 16) ^ swzc));
    f32x4 ao = f32x4{bias_o, bias_o, bias_o, bias_o};
    ao = __builtin_amdgcn_mfma_f32_16x16x32_bf16(ha0, wo[0], ao, 0, 0, 0);
    ao = __builtin_amdgcn_mfma_f32_16x16x32_bf16(ha1, wo[1], ao, 0, 0, 0);
    float* ob = out + (size_t)127 * 64;
    #pragma unroll
    for (int j = 0; j < 4; ++j)
      ob[ooff[j]] = ao[j];
  }
#undef HALF_STEP
}

extern "C" void kernel_launch(void* const* d_in, const int* in_sizes, int n_in,
                              void* d_out, int out_size, void* d_ws, size_t ws_size,
                              hipStream_t stream) {
  const float* s0    = (const float*)d_in[0];
  const float* a     = (const float*)d_in[1];
  const float* w_ih  = (const float*)d_in[2];
  const float* w_hh  = (const float*)d_in[3];
  const float* b_ih  = (const float*)d_in[4];
  const float* b_hh  = (const float*)d_in[5];
  const float* w_out = (const float*)d_in[6];
  const float* b_out = (const float*)d_in[7];
  float* out = (float*)d_out;
  hipLaunchKernelGGL(gru_fused, dim3(4096 / 16), dim3(256), 0, stream,
                     s0, a, w_ih, w_hh, b_ih, b_hh, w_out, b_out, out);
}